// Round 4
// baseline (226.232 us; speedup 1.0000x reference)
//
#include <hip/hip_runtime.h>

typedef unsigned short u16;
typedef __bf16 bf16;
typedef __attribute__((ext_vector_type(8))) __bf16 bf16x8;  // MFMA A/B frag (4 VGPRs)
typedef __attribute__((ext_vector_type(4))) float f32x4;    // MFMA C/D frag

#define AS1(p) ((const __attribute__((address_space(1))) void*)(p))
#define AS3(p) ((__attribute__((address_space(3))) void*)(p))

__device__ __forceinline__ u16 f2bf(float f) {
  unsigned u = __builtin_bit_cast(unsigned, f);
  u += 0x7fffu + ((u >> 16) & 1u);
  return (u16)(u >> 16);
}

static constexpr int  B_ = 2, N_ = 2048, C_ = 1024, H_ = 8, DH_ = 128;
static constexpr long SZ_IN = (long)B_ * N_ * C_;  // 4,194,304 elems
static constexpr long SZ_W  = (long)C_ * C_;       // 1,048,576 elems

// ---------------------------------------------------------------------------
// Fused cast kernel: y=0/1 -> input fp32->bf16 cast; y=2 -> weight
// cast+transpose (x<1024: matrix z=x>>8, 64x64 tile = x&255). One launch
// instead of two (fewer launch gaps; paths are block-uniform).
// ---------------------------------------------------------------------------
__global__ void k_cast(const float* __restrict__ q, const float* __restrict__ kv,
                       const float* __restrict__ W0, const float* __restrict__ W1,
                       const float* __restrict__ W2, const float* __restrict__ W3,
                       u16* __restrict__ qb, u16* __restrict__ kvb,
                       u16* __restrict__ WT)
{
  __shared__ u16 t[64][65];
  int tid = threadIdx.x;
  if (blockIdx.y < 2) {
    const float* src = blockIdx.y ? kv : q;
    u16* dst = blockIdx.y ? kvb : qb;
    long i = ((long)blockIdx.x * 256 + tid) * 8;
    float4 a = *(const float4*)(src + i);
    float4 b = *(const float4*)(src + i + 4);
    uint4 v;
    v.x = f2bf(a.x) | ((unsigned)f2bf(a.y) << 16);
    v.y = f2bf(a.z) | ((unsigned)f2bf(a.w) << 16);
    v.z = f2bf(b.x) | ((unsigned)f2bf(b.y) << 16);
    v.w = f2bf(b.z) | ((unsigned)f2bf(b.w) << 16);
    *(uint4*)(dst + i) = v;
    return;
  }
  int x = blockIdx.x;
  if (x >= 1024) return;
  int z = x >> 8, tile = x & 255;
  const float* W = (z == 0) ? W0 : (z == 1) ? W1 : (z == 2) ? W2 : W3;
  u16* dst = WT + (long)z * SZ_W;
  int n0 = (tile & 15) * 64, k0 = (tile >> 4) * 64;
#pragma unroll
  for (int r = 0; r < 4; ++r) {
    int slot = r * 256 + tid;
    int row = slot >> 4, c4 = slot & 15;
    float4 a = *(const float4*)(W + (long)(k0 + row) * 1024 + n0 + c4 * 4);
    t[c4*4+0][row] = f2bf(a.x);
    t[c4*4+1][row] = f2bf(a.y);
    t[c4*4+2][row] = f2bf(a.z);
    t[c4*4+3][row] = f2bf(a.w);
  }
  __syncthreads();
#pragma unroll
  for (int r = 0; r < 4; ++r) {
    int slot = r * 256 + tid;
    int row = slot >> 4, c4 = slot & 15;
    uint2 v;
    v.x = t[row][c4*4+0] | ((unsigned)t[row][c4*4+1] << 16);
    v.y = t[row][c4*4+2] | ((unsigned)t[row][c4*4+3] << 16);
    *(uint2*)(dst + (long)(n0 + row) * 1024 + k0 + c4 * 4) = v;
  }
}

// ---------------------------------------------------------------------------
// m97-style GEMM mainloop with XOR bank swizzle (round-2-proven, unchanged).
// ---------------------------------------------------------------------------
__device__ __forceinline__ void gemm_main_128x128(
    const u16* __restrict__ A, const u16* __restrict__ BT,
    u16* lA, u16* lB, int m0, int n0, int tid, f32x4 acc[4][4])
{
  int w = tid >> 6, l = tid & 63, quad = l >> 4, lm = l & 15;
  int wm = w >> 1, wn = w & 1;
  int srow = tid >> 2, schunk = tid & 3;
  int sxw = (srow >> 1) & 3;
  int sxr = (lm >> 1) & 3;
  const u16* Ag = A + (long)(m0 + srow) * 1024 + (schunk ^ sxw) * 8;
  const u16* Bg = BT + (long)(n0 + srow) * 1024 + (schunk ^ sxw) * 8;
  u16* lAw = lA + w * 512;
  u16* lBw = lB + w * 512;
  for (int kb = 0; kb < 32; ++kb) {
    const u16* Agk = Ag + kb * 32;
    const u16* Bgk = Bg + kb * 32;
    __builtin_amdgcn_global_load_lds(AS1(Agk),           AS3(lAw),        16, 0, 0);
    __builtin_amdgcn_global_load_lds(AS1(Agk + 64*1024), AS3(lAw + 2048), 16, 0, 0);
    __builtin_amdgcn_global_load_lds(AS1(Bgk),           AS3(lBw),        16, 0, 0);
    __builtin_amdgcn_global_load_lds(AS1(Bgk + 64*1024), AS3(lBw + 2048), 16, 0, 0);
    __syncthreads();
    bf16x8 af[4], bfr[4];
#pragma unroll
    for (int mi = 0; mi < 4; ++mi)
      af[mi] = *(const bf16x8*)(lA + (wm*64 + mi*16 + lm)*32 + ((quad ^ sxr))*8);
#pragma unroll
    for (int ni = 0; ni < 4; ++ni)
      bfr[ni] = *(const bf16x8*)(lB + (wn*64 + ni*16 + lm)*32 + ((quad ^ sxr))*8);
#pragma unroll
    for (int mi = 0; mi < 4; ++mi)
#pragma unroll
      for (int ni = 0; ni < 4; ++ni)
        acc[mi][ni] = __builtin_amdgcn_mfma_f32_16x16x32_bf16(af[mi], bfr[ni], acc[mi][ni], 0, 0, 0);
    __syncthreads();
  }
}

// ---------------------------------------------------------------------------
// QKV projection v2 (unchanged, r6/r7-proven).
// ---------------------------------------------------------------------------
__global__ __launch_bounds__(256, 3)
void k_gemm_qkv(const u16* __restrict__ qb, const u16* __restrict__ kvb,
                const u16* __restrict__ wt,
                const float* __restrict__ bq, const float* __restrict__ bk,
                const float* __restrict__ bv,
                u16* __restrict__ Qb, u16* __restrict__ Kb, u16* __restrict__ VTb)
{
  __shared__ u16 lA[4096], lB[4096];
  int tid = threadIdx.x;
  int z = blockIdx.z;
  f32x4 acc[4][4] = {};
  int w = tid >> 6, l = tid & 63, quad = l >> 4, lm = l & 15;
  int wm = w >> 1, wn = w & 1;

  if (z == 2) {
    int m0 = blockIdx.y * 128, n0 = blockIdx.x * 128;
    gemm_main_128x128(kvb, wt + 2 * SZ_W, lA, lB, m0, n0, tid, acc);
#pragma unroll
    for (int ni = 0; ni < 4; ++ni) {
      int n = n0 + wn*64 + ni*16 + lm;       // channel
      float bb = bv[n];
      int h = n >> 7, dd = n & 127;
#pragma unroll
      for (int mi = 0; mi < 4; ++mi) {
        int mbase = m0 + wm*64 + mi*16 + quad*4;  // token (4 consecutive)
        int bidx = mbase >> 11, nn = mbase & 2047;
        u16 o0 = f2bf(acc[mi][ni][0] + bb), o1 = f2bf(acc[mi][ni][1] + bb);
        u16 o2 = f2bf(acc[mi][ni][2] + bb), o3 = f2bf(acc[mi][ni][3] + bb);
        uint2 v; v.x = o0 | ((unsigned)o1 << 16); v.y = o2 | ((unsigned)o3 << 16);
        *(uint2*)(VTb + ((long)(bidx*8 + h)*128 + dd)*2048 + nn) = v;
      }
    }
  } else {
    const u16* X = (z == 0) ? qb : kvb;
    const float* bias = (z == 0) ? bq : bk;
    u16* dst = (z == 0) ? Qb : Kb;
    float scale = (z == 0) ? 0.08838834764831845f : 1.0f;  // fold 1/sqrt(128)
    int m0 = blockIdx.x * 128, n0 = blockIdx.y * 128;
    gemm_main_128x128(wt + (long)z * SZ_W, X, lA, lB, m0, n0, tid, acc);
#pragma unroll
    for (int mi = 0; mi < 4; ++mi) {
      int chb = m0 + wm*64 + mi*16 + quad*4;   // channel base (4 consecutive)
      int h = chb >> 7, d = chb & 127;
      float4 bb = *(const float4*)(bias + chb);
#pragma unroll
      for (int ni = 0; ni < 4; ++ni) {
        int tok = n0 + wn*64 + ni*16 + lm;
        int bidx = tok >> 11, nn = tok & 2047;
        u16 o0 = f2bf((acc[mi][ni][0] + bb.x) * scale);
        u16 o1 = f2bf((acc[mi][ni][1] + bb.y) * scale);
        u16 o2 = f2bf((acc[mi][ni][2] + bb.z) * scale);
        u16 o3 = f2bf((acc[mi][ni][3] + bb.w) * scale);
        uint2 v; v.x = o0 | ((unsigned)o1 << 16); v.y = o2 | ((unsigned)o3 << 16);
        *(uint2*)(dst + ((long)(bidx*8 + h)*2048 + nn)*128 + d) = v;
      }
    }
  }
}

// ---------------------------------------------------------------------------
// Flash attention v12 — v11 + 32 q-rows/wave (LDS-read amortization).
//
// v11 (62.2us): counters hit the pre-registered LDS-bound discriminator
// (MfmaUtil 20.7, VALU 25.5, HBM 4.2%): per block-tile LDS reads = 8 waves x
// (8 kf + 8 vf + 1 pf) x 1KB = 136KB ~ 1640cy at 85 B/cyc (m134) + 256
// conflict-cy + writes ~ 2000 of the 2333 cy/tile. The LDS unit is the pipe.
// Reuse lever: each wave reads the WHOLE shared K/V tile regardless of its
// q-rows, so kf+vf bytes per MFMA scale as 1/(q-rows per wave).
//
// v12: same grid (16,16), same staging, same swizzles, but 4 waves x 32
// q-rows (256 thr) instead of 8 x 16. Per-tile LDS reads 136KB -> 72KB
// (4 x (8 kf + 8 vf + 2 pf) KB) for identical MFMA work and TA traffic.
// Each wave: 2 K-DMA + 2 V-DMA per tile (512 chunks / 256 lanes).
// K LDS: 32 rows x 16 chunks, chunk stored at c^(r&7)  (v8-proven).
// V LDS: row-pair [dd=d>>1][slot], content slot = c2^(dd&7), c2=(d&1)*4+c
//        (v11-proven; DMA dest lane-linear, swizzle on global src).
// P: per-wave 2KB swizzled round-trip (v8-proven formulas, mi=2 groups).
// LDS u16: bufK 2x4096 [0,8192) | bufV 2x4096 [8192,16384) | lP 4x1024
// [16384,20480) = 40KB.
// ---------------------------------------------------------------------------
__global__ __launch_bounds__(256, 2)
void k_attn(const u16* __restrict__ Qb, const u16* __restrict__ Kb,
            const u16* __restrict__ VTb, u16* __restrict__ Sout)
{
  __shared__ u16 smem[20480];   // 40 KB
  u16* lP = smem + 16384;

  int tid = threadIdx.x;
  int w = tid >> 6, l = tid & 63, quad = l >> 4, lm = l & 15;
  int bh = blockIdx.x;             // XCD = bh % 8 -> 2 bh per XCD L2
  int q0 = blockIdx.y * 128 + w * 32;
  const u16* Qg = Qb + ((long)bh * 2048 + q0) * 128;
  const u16* Kg = Kb + (long)bh * 2048 * 128;
  const u16* Vg = VTb + (long)bh * 128 * 2048;
  u16* lPw = lP + w * 1024;

  // register-resident Q (32 q-rows, DH=128), scale pre-folded at projection
  bf16x8 qf[2][4];
#pragma unroll
  for (int mi = 0; mi < 2; ++mi)
#pragma unroll
    for (int kk = 0; kk < 4; ++kk)
      qf[mi][kk] = *(const bf16x8*)(Qg + (long)(mi*16 + lm)*128 + kk*32 + quad*8);

  f32x4 accO[2][8] = {};
  float sumP[2][4] = {};

  // Cooperative staging: per tile each wave issues 2 K-DMA + 2 V-DMA
  // (4 waves x 2 x 64 lanes = 512 chunks of 16B each for K and for V).
  auto stage = [&](int tt) {
    int buf = (tt & 1) * 4096;
#pragma unroll
    for (int j = 0; j < 2; ++j) {
      int s = (w*2 + j)*64 + l;        // 0..511
      int r = s >> 4, c = s & 15;      // key row, chunk
      __builtin_amdgcn_global_load_lds(
          AS1(Kg + (long)(tt*32 + r)*128 + ((c ^ (r & 7)) * 8)),
          AS3(smem + buf + (w*2 + j)*512), 16, 0, 0);
    }
#pragma unroll
    for (int j = 0; j < 2; ++j) {
      int s = (w*2 + j)*64 + l;        // 0..511
      int dd = s >> 3, slot = s & 7;   // d row-pair, stored slot
      int c2 = slot ^ (dd & 7);        // logical chunk in row-pair
      int d  = dd*2 + (c2 >> 2);       // d row 0..127
      int c  = c2 & 3;                 // chunk within d row
      __builtin_amdgcn_global_load_lds(
          AS1(Vg + (long)d*2048 + tt*32 + c*8),
          AS3(smem + 8192 + buf + (w*2 + j)*512), 16, 0, 0);
    }
  };

  stage(0);

#pragma unroll 1
  for (int t = 0; t < 64; ++t) {
    __syncthreads();          // drains stage(t) DMA; WAR-protects buf (t+1)&1
    if (t < 63) stage(t + 1);

    const u16* bK = smem + (t & 1) * 4096;
    const u16* bV = smem + 8192 + (t & 1) * 4096;

    // QK^T: 32q x 32k from shared LDS K tile
    f32x4 accS[2][2] = {};
#pragma unroll
    for (int kk = 0; kk < 4; ++kk)
#pragma unroll
      for (int ni = 0; ni < 2; ++ni) {
        bf16x8 kf = *(const bf16x8*)(bK + (ni*16 + lm)*128 + (((kk*4 + quad) ^ (lm & 7)))*8);
#pragma unroll
        for (int mi = 0; mi < 2; ++mi)
          accS[mi][ni] = __builtin_amdgcn_mfma_f32_16x16x32_bf16(qf[mi][kk], kf, accS[mi][ni], 0, 0, 0);
      }

    // V B-frags from shared LDS V tile (2-way conflict-free by construction)
    bf16x8 vf[8];
#pragma unroll
    for (int ni = 0; ni < 8; ++ni) {
      int dd = ni*8 + (lm >> 1);
      int slot = (((lm & 1)*4 + quad) ^ (lm >> 1));
      vf[ni] = *(const bf16x8*)(bV + dd*64 + slot*8);
    }

    // no-max softmax: p = exp(s); per-lane partial sums; P -> swizzled LDS
#pragma unroll
    for (int mi = 0; mi < 2; ++mi)
#pragma unroll
      for (int r = 0; r < 4; ++r) {
        int R = mi*16 + quad*4 + r;
        int xr = (quad*2 + (r >> 1)) & 3;
#pragma unroll
        for (int ni = 0; ni < 2; ++ni) {
          float p = __expf(accS[mi][ni][r]);
          sumP[mi][r] += p;
          int ch = ni*2 + (lm >> 3);
          lPw[(R*4 + (ch ^ xr))*8 + (lm & 7)] = f2bf(p);
        }
      }

    // P A-frags (own wave's LDS region; compiler inserts lgkmcnt wait)
    bf16x8 pf[2];
#pragma unroll
    for (int mi = 0; mi < 2; ++mi)
      pf[mi] = *(const bf16x8*)(lPw + ((mi*16 + lm)*4 + (quad ^ ((lm >> 1) & 3)))*8);

    // O += P V
#pragma unroll
    for (int ni = 0; ni < 8; ++ni)
#pragma unroll
      for (int mi = 0; mi < 2; ++mi)
        accO[mi][ni] = __builtin_amdgcn_mfma_f32_16x16x32_bf16(pf[mi], vf[ni], accO[mi][ni], 0, 0, 0);
  }

  // ---- row-sum reduce (16 col-lanes per row) + normalize + store ----
  // Each wave owns its 32 rows completely: no cross-wave merge needed.
  int b = bh >> 3, h = bh & 7;
#pragma unroll
  for (int mi = 0; mi < 2; ++mi)
#pragma unroll
    for (int r = 0; r < 4; ++r) {
      float s = sumP[mi][r];
      s += __shfl_xor(s, 1);
      s += __shfl_xor(s, 2);
      s += __shfl_xor(s, 4);
      s += __shfl_xor(s, 8);
      float linv = 1.f / s;
#pragma unroll
      for (int ni = 0; ni < 8; ++ni) {
        float v = accO[mi][ni][r] * linv;
        Sout[((long)(b*2048 + q0 + mi*16 + quad*4 + r))*1024 + h*128 + ni*16 + lm] = f2bf(v);
      }
    }
}

// ---------------------------------------------------------------------------
// Output projection v2 (unchanged, r6/r7-proven).
// ---------------------------------------------------------------------------
__global__ __launch_bounds__(256, 3)
void k_gemm_out(const u16* __restrict__ S, const u16* __restrict__ WoT,
                const float* __restrict__ bo, float* __restrict__ out)
{
  __shared__ u16 lA[4096], lB[4096];
  int tid = threadIdx.x;
  int m0 = blockIdx.x * 128, n0 = blockIdx.y * 128;   // m = channel, n = token
  f32x4 acc[4][4] = {};
  gemm_main_128x128(WoT, S, lA, lB, m0, n0, tid, acc);

  int w = tid >> 6, l = tid & 63, quad = l >> 4, lm = l & 15;
  int wm = w >> 1, wn = w & 1;
#pragma unroll
  for (int mi = 0; mi < 4; ++mi) {
    int chb = m0 + wm*64 + mi*16 + quad*4;   // 4 consecutive channels
    float4 bb = *(const float4*)(bo + chb);
#pragma unroll
    for (int ni = 0; ni < 4; ++ni) {
      int tok = n0 + wn*64 + ni*16 + lm;
      float4 v;
      v.x = acc[mi][ni][0] + bb.x;
      v.y = acc[mi][ni][1] + bb.y;
      v.z = acc[mi][ni][2] + bb.z;
      v.w = acc[mi][ni][3] + bb.w;
      *(float4*)(out + (long)tok * 1024 + chb) = v;
    }
  }
}

// ---------------------------------------------------------------------------
// ws layout (u16 elems), 48 MiB: ABUF (q_bf16, reused for summed), KVB,
// WT 4x, Qb/Kb [b][h][n][d], VTb [b][h][d][n]
// ---------------------------------------------------------------------------
extern "C" void kernel_launch(void* const* d_in, const int* in_sizes, int n_in,
                              void* d_out, int out_size, void* d_ws, size_t ws_size,
                              hipStream_t stream)
{
  const float* inq  = (const float*)d_in[0];
  const float* inkv = (const float*)d_in[1];
  const float* Wq = (const float*)d_in[2];
  const float* bq = (const float*)d_in[3];
  const float* Wk = (const float*)d_in[4];
  const float* bk = (const float*)d_in[5];
  const float* Wv = (const float*)d_in[6];
  const float* bv = (const float*)d_in[7];
  const float* Wo = (const float*)d_in[8];
  const float* bo = (const float*)d_in[9];

  u16* ws   = (u16*)d_ws;
  u16* ABUF = ws;
  u16* KVB  = ws + SZ_IN;
  u16* WT   = ws + 2 * SZ_IN;
  u16* Qb   = WT + 4 * SZ_W;
  u16* Kb   = Qb + SZ_IN;
  u16* VTb  = Kb + SZ_IN;

  k_cast    <<<dim3(2048, 3),   256, 0, stream>>>(inq, inkv, Wq, Wk, Wv, Wo, ABUF, KVB, WT);
  k_gemm_qkv<<<dim3(8, 32, 3),  256, 0, stream>>>(ABUF, KVB, WT, bq, bk, bv, Qb, Kb, VTb);
  k_attn    <<<dim3(16, 16),    256, 0, stream>>>(Qb, Kb, VTb, ABUF);
  k_gemm_out<<<dim3(8, 32),     256, 0, stream>>>(ABUF, WT + 3 * SZ_W, bo, (float*)d_out);
}

// Round 5
// 215.834 us; speedup vs baseline: 1.0482x; 1.0482x over previous
//
#include <hip/hip_runtime.h>

typedef unsigned short u16;
typedef __bf16 bf16;
typedef __attribute__((ext_vector_type(8))) __bf16 bf16x8;  // MFMA A/B frag (4 VGPRs)
typedef __attribute__((ext_vector_type(4))) float f32x4;    // MFMA C/D frag

#define AS1(p) ((const __attribute__((address_space(1))) void*)(p))
#define AS3(p) ((__attribute__((address_space(3))) void*)(p))

__device__ __forceinline__ u16 f2bf(float f) {
  unsigned u = __builtin_bit_cast(unsigned, f);
  u += 0x7fffu + ((u >> 16) & 1u);
  return (u16)(u >> 16);
}

static constexpr int  B_ = 2, N_ = 2048, C_ = 1024, H_ = 8, DH_ = 128;
static constexpr long SZ_IN = (long)B_ * N_ * C_;  // 4,194,304 elems
static constexpr long SZ_W  = (long)C_ * C_;       // 1,048,576 elems

// ---------------------------------------------------------------------------
// Fused cast kernel: y=0/1 -> input fp32->bf16 cast; y=2 -> weight
// cast+transpose (x<1024: matrix z=x>>8, 64x64 tile = x&255). One launch
// instead of two (fewer launch gaps; paths are block-uniform).
// ---------------------------------------------------------------------------
__global__ void k_cast(const float* __restrict__ q, const float* __restrict__ kv,
                       const float* __restrict__ W0, const float* __restrict__ W1,
                       const float* __restrict__ W2, const float* __restrict__ W3,
                       u16* __restrict__ qb, u16* __restrict__ kvb,
                       u16* __restrict__ WT)
{
  __shared__ u16 t[64][65];
  int tid = threadIdx.x;
  if (blockIdx.y < 2) {
    const float* src = blockIdx.y ? kv : q;
    u16* dst = blockIdx.y ? kvb : qb;
    long i = ((long)blockIdx.x * 256 + tid) * 8;
    float4 a = *(const float4*)(src + i);
    float4 b = *(const float4*)(src + i + 4);
    uint4 v;
    v.x = f2bf(a.x) | ((unsigned)f2bf(a.y) << 16);
    v.y = f2bf(a.z) | ((unsigned)f2bf(a.w) << 16);
    v.z = f2bf(b.x) | ((unsigned)f2bf(b.y) << 16);
    v.w = f2bf(b.z) | ((unsigned)f2bf(b.w) << 16);
    *(uint4*)(dst + i) = v;
    return;
  }
  int x = blockIdx.x;
  if (x >= 1024) return;
  int z = x >> 8, tile = x & 255;
  const float* W = (z == 0) ? W0 : (z == 1) ? W1 : (z == 2) ? W2 : W3;
  u16* dst = WT + (long)z * SZ_W;
  int n0 = (tile & 15) * 64, k0 = (tile >> 4) * 64;
#pragma unroll
  for (int r = 0; r < 4; ++r) {
    int slot = r * 256 + tid;
    int row = slot >> 4, c4 = slot & 15;
    float4 a = *(const float4*)(W + (long)(k0 + row) * 1024 + n0 + c4 * 4);
    t[c4*4+0][row] = f2bf(a.x);
    t[c4*4+1][row] = f2bf(a.y);
    t[c4*4+2][row] = f2bf(a.z);
    t[c4*4+3][row] = f2bf(a.w);
  }
  __syncthreads();
#pragma unroll
  for (int r = 0; r < 4; ++r) {
    int slot = r * 256 + tid;
    int row = slot >> 4, c4 = slot & 15;
    uint2 v;
    v.x = t[row][c4*4+0] | ((unsigned)t[row][c4*4+1] << 16);
    v.y = t[row][c4*4+2] | ((unsigned)t[row][c4*4+3] << 16);
    *(uint2*)(dst + (long)(n0 + row) * 1024 + k0 + c4 * 4) = v;
  }
}

// ---------------------------------------------------------------------------
// m97-style GEMM mainloop with XOR bank swizzle (round-2-proven, unchanged).
// ---------------------------------------------------------------------------
__device__ __forceinline__ void gemm_main_128x128(
    const u16* __restrict__ A, const u16* __restrict__ BT,
    u16* lA, u16* lB, int m0, int n0, int tid, f32x4 acc[4][4])
{
  int w = tid >> 6, l = tid & 63, quad = l >> 4, lm = l & 15;
  int wm = w >> 1, wn = w & 1;
  int srow = tid >> 2, schunk = tid & 3;
  int sxw = (srow >> 1) & 3;
  int sxr = (lm >> 1) & 3;
  const u16* Ag = A + (long)(m0 + srow) * 1024 + (schunk ^ sxw) * 8;
  const u16* Bg = BT + (long)(n0 + srow) * 1024 + (schunk ^ sxw) * 8;
  u16* lAw = lA + w * 512;
  u16* lBw = lB + w * 512;
  for (int kb = 0; kb < 32; ++kb) {
    const u16* Agk = Ag + kb * 32;
    const u16* Bgk = Bg + kb * 32;
    __builtin_amdgcn_global_load_lds(AS1(Agk),           AS3(lAw),        16, 0, 0);
    __builtin_amdgcn_global_load_lds(AS1(Agk + 64*1024), AS3(lAw + 2048), 16, 0, 0);
    __builtin_amdgcn_global_load_lds(AS1(Bgk),           AS3(lBw),        16, 0, 0);
    __builtin_amdgcn_global_load_lds(AS1(Bgk + 64*1024), AS3(lBw + 2048), 16, 0, 0);
    __syncthreads();
    bf16x8 af[4], bfr[4];
#pragma unroll
    for (int mi = 0; mi < 4; ++mi)
      af[mi] = *(const bf16x8*)(lA + (wm*64 + mi*16 + lm)*32 + ((quad ^ sxr))*8);
#pragma unroll
    for (int ni = 0; ni < 4; ++ni)
      bfr[ni] = *(const bf16x8*)(lB + (wn*64 + ni*16 + lm)*32 + ((quad ^ sxr))*8);
#pragma unroll
    for (int mi = 0; mi < 4; ++mi)
#pragma unroll
      for (int ni = 0; ni < 4; ++ni)
        acc[mi][ni] = __builtin_amdgcn_mfma_f32_16x16x32_bf16(af[mi], bfr[ni], acc[mi][ni], 0, 0, 0);
    __syncthreads();
  }
}

// ---------------------------------------------------------------------------
// QKV projection v2 (unchanged, r6/r7-proven).
// ---------------------------------------------------------------------------
__global__ __launch_bounds__(256, 3)
void k_gemm_qkv(const u16* __restrict__ qb, const u16* __restrict__ kvb,
                const u16* __restrict__ wt,
                const float* __restrict__ bq, const float* __restrict__ bk,
                const float* __restrict__ bv,
                u16* __restrict__ Qb, u16* __restrict__ Kb, u16* __restrict__ VTb)
{
  __shared__ u16 lA[4096], lB[4096];
  int tid = threadIdx.x;
  int z = blockIdx.z;
  f32x4 acc[4][4] = {};
  int w = tid >> 6, l = tid & 63, quad = l >> 4, lm = l & 15;
  int wm = w >> 1, wn = w & 1;

  if (z == 2) {
    int m0 = blockIdx.y * 128, n0 = blockIdx.x * 128;
    gemm_main_128x128(kvb, wt + 2 * SZ_W, lA, lB, m0, n0, tid, acc);
#pragma unroll
    for (int ni = 0; ni < 4; ++ni) {
      int n = n0 + wn*64 + ni*16 + lm;       // channel
      float bb = bv[n];
      int h = n >> 7, dd = n & 127;
#pragma unroll
      for (int mi = 0; mi < 4; ++mi) {
        int mbase = m0 + wm*64 + mi*16 + quad*4;  // token (4 consecutive)
        int bidx = mbase >> 11, nn = mbase & 2047;
        u16 o0 = f2bf(acc[mi][ni][0] + bb), o1 = f2bf(acc[mi][ni][1] + bb);
        u16 o2 = f2bf(acc[mi][ni][2] + bb), o3 = f2bf(acc[mi][ni][3] + bb);
        uint2 v; v.x = o0 | ((unsigned)o1 << 16); v.y = o2 | ((unsigned)o3 << 16);
        *(uint2*)(VTb + ((long)(bidx*8 + h)*128 + dd)*2048 + nn) = v;
      }
    }
  } else {
    const u16* X = (z == 0) ? qb : kvb;
    const float* bias = (z == 0) ? bq : bk;
    u16* dst = (z == 0) ? Qb : Kb;
    float scale = (z == 0) ? 0.08838834764831845f : 1.0f;  // fold 1/sqrt(128)
    int m0 = blockIdx.x * 128, n0 = blockIdx.y * 128;
    gemm_main_128x128(wt + (long)z * SZ_W, X, lA, lB, m0, n0, tid, acc);
#pragma unroll
    for (int mi = 0; mi < 4; ++mi) {
      int chb = m0 + wm*64 + mi*16 + quad*4;   // channel base (4 consecutive)
      int h = chb >> 7, d = chb & 127;
      float4 bb = *(const float4*)(bias + chb);
#pragma unroll
      for (int ni = 0; ni < 4; ++ni) {
        int tok = n0 + wn*64 + ni*16 + lm;
        int bidx = tok >> 11, nn = tok & 2047;
        u16 o0 = f2bf((acc[mi][ni][0] + bb.x) * scale);
        u16 o1 = f2bf((acc[mi][ni][1] + bb.y) * scale);
        u16 o2 = f2bf((acc[mi][ni][2] + bb.z) * scale);
        u16 o3 = f2bf((acc[mi][ni][3] + bb.w) * scale);
        uint2 v; v.x = o0 | ((unsigned)o1 << 16); v.y = o2 | ((unsigned)o3 << 16);
        *(uint2*)(dst + ((long)(bidx*8 + h)*2048 + nn)*128 + d) = v;
      }
    }
  }
}

// ---------------------------------------------------------------------------
// Flash attention v13 — v11 + KVBLK=64 (fixed per-tile cost amortization).
//
// Evidence chain: v11 (8w x 16 rows, 2333 cy/tile) vs v12 (4w x 32 rows,
// 2482 cy/tile): total per-SIMD issue work per tile identical -> time
// identical, though v12 halved LDS reads AND bank conflicts. So neither
// LDS reads nor conflicts bind. Per-SIMD accounting (16x16x32 MFMA holds
// the SIMD matrix pipe ~19.4 cyc): MFMA 621 + VALU ~580 of 2333 cyc/tile;
// the missing ~1100 cyc/tile is FIXED per-tile cost (barrier drain, kf
// latency ramp, accS chain startup, P round-trip) paid 64 times.
//
// v13 = v11 with tile depth doubled (KVBLK=64, 32 iterations): per-tile
// pipe work doubles, fixed cost paid half as often. Everything else is
// v11-proven index-for-index: 8 waves x 16 q-rows, QBLK=128, grid (16,16),
// double-buffered DMA staging, K chunk-XOR swizzle, V per-d-row swizzle
// (8 chunks/row now), P round-trip per 32-key half (exact v11 formulas).
// LDS u16: bufK 2x8192 [0,16384) | bufV 2x8192 [16384,32768) | lP 8x1024
// [32768,40960) = 80 KB (gfx950 allows >64KB/WG; grid is 1 block/CU).
// ---------------------------------------------------------------------------
__global__ __launch_bounds__(512, 2)
void k_attn(const u16* __restrict__ Qb, const u16* __restrict__ Kb,
            const u16* __restrict__ VTb, u16* __restrict__ Sout)
{
  __shared__ u16 smem[40960];   // 80 KB
  u16* lP = smem + 32768;

  int tid = threadIdx.x;
  int w = tid >> 6, l = tid & 63, quad = l >> 4, lm = l & 15;
  int bh = blockIdx.x;             // XCD = bh % 8 -> 2 bh per XCD L2
  int q0 = blockIdx.y * 128 + w * 16;
  const u16* Qg = Qb + ((long)bh * 2048 + q0) * 128;
  const u16* Kg = Kb + (long)bh * 2048 * 128;
  const u16* Vg = VTb + (long)bh * 128 * 2048;
  u16* lPw = lP + w * 1024;

  // register-resident Q (16 q-rows, DH=128), scale pre-folded at projection
  bf16x8 qf[4];
#pragma unroll
  for (int kk = 0; kk < 4; ++kk)
    qf[kk] = *(const bf16x8*)(Qg + (long)lm * 128 + kk*32 + quad*8);

  f32x4 accO[8] = {};
  float sumP[4] = {};

  // Cooperative staging of a 64-key tile: K 64x128 (1024 16B chunks) and
  // V 128x64 (1024 chunks); 512 lanes x 2 DMA each for K and for V.
  // K: chunk stored at c^(r&7) within row (v8/v11-proven).
  // V: per d-row 8 chunks, stored slot = c^(d&7); DMA dest lane-linear,
  // swizzle applied to the global source address (m173 pattern).
  auto stage = [&](int tt) {
    int buf = (tt & 1) * 8192;
#pragma unroll
    for (int j = 0; j < 2; ++j) {
      int s = j*512 + tid;             // 0..1023
      int r = s >> 4, c = s & 15;      // key row 0..63, chunk 0..15
      __builtin_amdgcn_global_load_lds(
          AS1(Kg + (long)(tt*64 + r)*128 + ((c ^ (r & 7)) * 8)),
          AS3(smem + buf + (j*512 + w*64)*8), 16, 0, 0);
    }
#pragma unroll
    for (int j = 0; j < 2; ++j) {
      int s = j*512 + tid;             // 0..1023
      int d = s >> 3, slot = s & 7;    // d row 0..127, stored slot
      int c = slot ^ (d & 7);          // logical chunk (8 per 64-key row)
      __builtin_amdgcn_global_load_lds(
          AS1(Vg + (long)d*2048 + tt*64 + c*8),
          AS3(smem + 16384 + buf + (j*512 + w*64)*8), 16, 0, 0);
    }
  };

  stage(0);

#pragma unroll 1
  for (int t = 0; t < 32; ++t) {
    __syncthreads();          // drains stage(t) DMA; WAR-protects buf (t+1)&1
    if (t < 31) stage(t + 1);

    const u16* bK = smem + (t & 1) * 8192;
    const u16* bV = smem + 16384 + (t & 1) * 8192;

    // QK^T: 16q x 64k from shared LDS K tile
    f32x4 accS[4] = {};
#pragma unroll
    for (int kk = 0; kk < 4; ++kk)
#pragma unroll
      for (int ni = 0; ni < 4; ++ni) {
        bf16x8 kf = *(const bf16x8*)(bK + (ni*16 + lm)*128 + (((kk*4 + quad) ^ (lm & 7)))*8);
        accS[ni] = __builtin_amdgcn_mfma_f32_16x16x32_bf16(qf[kk], kf, accS[ni], 0, 0, 0);
      }

    // V B-frags for key-half 0 issued early (independent of softmax)
    bf16x8 vfk[8];
#pragma unroll
    for (int ni = 0; ni < 8; ++ni)
      vfk[ni] = *(const bf16x8*)(bV + ((ni*16 + lm)*8 + ((0*4 + quad) ^ (lm & 7)))*8);

    // no-max softmax: p = exp(s); per-lane partial sums; P -> swizzled LDS
    // (two 32-key halves, v11 formulas per half)
#pragma unroll
    for (int r = 0; r < 4; ++r) {
      int R = quad*4 + r;
      int xr = (quad*2 + (r >> 1)) & 3;
#pragma unroll
      for (int ni = 0; ni < 4; ++ni) {
        float p = __expf(accS[ni][r]);
        sumP[r] += p;
        int kh = ni >> 1;
        int ch = (ni & 1)*2 + (lm >> 3);
        lPw[kh*512 + (R*4 + (ch ^ xr))*8 + (lm & 7)] = f2bf(p);
      }
    }

    // key-half 0: P A-frag + PV
    bf16x8 pf = *(const bf16x8*)(lPw + (lm*4 + (quad ^ ((lm >> 1) & 3)))*8);
#pragma unroll
    for (int ni = 0; ni < 8; ++ni)
      accO[ni] = __builtin_amdgcn_mfma_f32_16x16x32_bf16(pf, vfk[ni], accO[ni], 0, 0, 0);

    // key-half 1: V frags, P A-frag, PV
#pragma unroll
    for (int ni = 0; ni < 8; ++ni)
      vfk[ni] = *(const bf16x8*)(bV + ((ni*16 + lm)*8 + ((1*4 + quad) ^ (lm & 7)))*8);
    pf = *(const bf16x8*)(lPw + 512 + (lm*4 + (quad ^ ((lm >> 1) & 3)))*8);
#pragma unroll
    for (int ni = 0; ni < 8; ++ni)
      accO[ni] = __builtin_amdgcn_mfma_f32_16x16x32_bf16(pf, vfk[ni], accO[ni], 0, 0, 0);
  }

  // ---- row-sum reduce (16 col-lanes per row) + normalize + store ----
  // Each wave owns its 16 rows completely: no cross-wave merge needed.
  int b = bh >> 3, h = bh & 7;
#pragma unroll
  for (int r = 0; r < 4; ++r) {
    float s = sumP[r];
    s += __shfl_xor(s, 1);
    s += __shfl_xor(s, 2);
    s += __shfl_xor(s, 4);
    s += __shfl_xor(s, 8);
    float linv = 1.f / s;
#pragma unroll
    for (int ni = 0; ni < 8; ++ni) {
      float v = accO[ni][r] * linv;
      Sout[((long)(b*2048 + q0 + quad*4 + r))*1024 + h*128 + ni*16 + lm] = f2bf(v);
    }
  }
}

// ---------------------------------------------------------------------------
// Output projection v2 (unchanged, r6/r7-proven).
// ---------------------------------------------------------------------------
__global__ __launch_bounds__(256, 3)
void k_gemm_out(const u16* __restrict__ S, const u16* __restrict__ WoT,
                const float* __restrict__ bo, float* __restrict__ out)
{
  __shared__ u16 lA[4096], lB[4096];
  int tid = threadIdx.x;
  int m0 = blockIdx.x * 128, n0 = blockIdx.y * 128;   // m = channel, n = token
  f32x4 acc[4][4] = {};
  gemm_main_128x128(WoT, S, lA, lB, m0, n0, tid, acc);

  int w = tid >> 6, l = tid & 63, quad = l >> 4, lm = l & 15;
  int wm = w >> 1, wn = w & 1;
#pragma unroll
  for (int mi = 0; mi < 4; ++mi) {
    int chb = m0 + wm*64 + mi*16 + quad*4;   // 4 consecutive channels
    float4 bb = *(const float4*)(bo + chb);
#pragma unroll
    for (int ni = 0; ni < 4; ++ni) {
      int tok = n0 + wn*64 + ni*16 + lm;
      float4 v;
      v.x = acc[mi][ni][0] + bb.x;
      v.y = acc[mi][ni][1] + bb.y;
      v.z = acc[mi][ni][2] + bb.z;
      v.w = acc[mi][ni][3] + bb.w;
      *(float4*)(out + (long)tok * 1024 + chb) = v;
    }
  }
}

// ---------------------------------------------------------------------------
// ws layout (u16 elems), 48 MiB: ABUF (q_bf16, reused for summed), KVB,
// WT 4x, Qb/Kb [b][h][n][d], VTb [b][h][d][n]
// ---------------------------------------------------------------------------
extern "C" void kernel_launch(void* const* d_in, const int* in_sizes, int n_in,
                              void* d_out, int out_size, void* d_ws, size_t ws_size,
                              hipStream_t stream)
{
  const float* inq  = (const float*)d_in[0];
  const float* inkv = (const float*)d_in[1];
  const float* Wq = (const float*)d_in[2];
  const float* bq = (const float*)d_in[3];
  const float* Wk = (const float*)d_in[4];
  const float* bk = (const float*)d_in[5];
  const float* Wv = (const float*)d_in[6];
  const float* bv = (const float*)d_in[7];
  const float* Wo = (const float*)d_in[8];
  const float* bo = (const float*)d_in[9];

  u16* ws   = (u16*)d_ws;
  u16* ABUF = ws;
  u16* KVB  = ws + SZ_IN;
  u16* WT   = ws + 2 * SZ_IN;
  u16* Qb   = WT + 4 * SZ_W;
  u16* Kb   = Qb + SZ_IN;
  u16* VTb  = Kb + SZ_IN;

  k_cast    <<<dim3(2048, 3),   256, 0, stream>>>(inq, inkv, Wq, Wk, Wv, Wo, ABUF, KVB, WT);
  k_gemm_qkv<<<dim3(8, 32, 3),  256, 0, stream>>>(ABUF, KVB, WT, bq, bk, bv, Qb, Kb, VTb);
  k_attn    <<<dim3(16, 16),    512, 0, stream>>>(Qb, Kb, VTb, ABUF);
  k_gemm_out<<<dim3(8, 32),     256, 0, stream>>>(ABUF, WT + 3 * SZ_W, bo, (float*)d_out);
}